// Round 3
// baseline (180.391 us; speedup 1.0000x reference)
//
#include <hip/hip_runtime.h>
#include <hip/hip_bf16.h>

#define R_ 3
#define D_ 7            // 2R+1
#define W_ 49
#define N_ 128
#define K_ 131
#define C_ 21
#define B_ 2
#define NN (N_ * N_)
#define TI_ 8                   // tile rows
#define TJ_ 16                  // tile cols
#define PROWS (TI_ + 2 * R_)    // 14
#define PCOLS (TJ_ + 2 * R_)    // 22
#define PSTR 24                 // LDS row stride
#define NELEM (PROWS * PCOLS)   // 308 staged elements
#define LDSZ ((PROWS + 1) * PSTR + 8)  // +1 row pad absorbs dummy reads/spare writes
#define KC 8                    // k-chunks per tile
#define KCHUNK ((K_ + KC - 1) / KC)    // 17
#define HW 25                   // w's per half-thread

// Kernel A: per-pixel window softmax over channels, weighted by conv_parameter.
// Lane pairs (2t, 2t+1) share a pixel; h=tid&1 owns w = 2*idx+h (even/odd taps).
// Aout layout: [B][W][NN], partial-accumulated with atomics across KC chunks.
__global__ __launch_bounds__(256) void rwn_affinity(
    const float* __restrict__ feats,   // [B,K,N,N]
    const int*   __restrict__ mask,    // [B,N,N]
    const float* __restrict__ cp,      // [K]
    float* __restrict__ Aout)          // [B,W,NN] (pre-zeroed)
{
    __shared__ float patchf[LDSZ];

    const int tile = blockIdx.x;           // 0..127  (16 x 8 tiles of 8x16)
    const int kc   = blockIdx.y;           // 0..KC-1
    const int b    = blockIdx.z;           // 0..B-1
    const int tr = tile >> 3, tc = tile & 7;
    const int ti0 = tr * TI_, tj0 = tc * TJ_;

    const int tid = threadIdx.x;
    const int pix = tid >> 1;              // 0..127
    const int h   = tid & 1;               // even/odd tap owner
    const int ti = pix >> 4;               // 0..7
    const int tj = pix & 15;               // 0..15
    const int gi = ti0 + ti, gj = tj0 + tj;

    // ---- Hoisted staging setup: thread owns element tid, and 256+tid if tid<52
    int   soff[2];
    float swt[2];
    int   slds[2];
    #pragma unroll
    for (int r = 0; r < 2; ++r) {
        int e = tid + r * 256;
        bool act = (e < NELEM);
        int pr = e / PCOLS, pc = e - pr * PCOLS;
        int mi = ti0 + pr - R_, mj = tj0 + pc - R_;
        bool valid = act && mi >= 0 && mi < N_ && mj >= 0 && mj < N_;
        int cmi = mi < 0 ? 0 : (mi > N_ - 1 ? N_ - 1 : mi);
        int cmj = mj < 0 ? 0 : (mj > N_ - 1 ? N_ - 1 : mj);
        soff[r] = cmi * N_ + cmj;
        swt[r]  = valid ? (float)mask[b * NN + soff[r]] : 0.f;
        slds[r] = act ? (pr * PSTR + pc) : (PROWS * PSTR + 4);  // spare pad slot
    }

    // Window validity bits for this thread's 25 taps (w = 2*idx + h; w<49 & in grid)
    unsigned int vmask = 0u;
    #pragma unroll
    for (int idx = 0; idx < HW; ++idx) {
        int w = 2 * idx + h;
        int u = w / D_, v = w - u * D_;
        int ni = gi + u - R_, nj = gj + v - R_;
        if (w < W_ && ni >= 0 && ni < N_ && nj >= 0 && nj < N_)
            vmask |= (1u << idx);
    }

    // LDS base registers: base for center; bN (+h) for normal taps; bX for taps
    // whose even partner sits at v==6 (odd tap wraps to next row: delta=PSTR-6).
    const int base = ti * PSTR + tj;
    const int bN = base + h;
    const int bX = base + (h ? (PSTR - 6) : 0);

    float Aacc[HW];
    #pragma unroll
    for (int i = 0; i < HW; ++i) Aacc[i] = 0.f;

    const int k0 = kc * KCHUNK;
    const int k1 = (k0 + KCHUNK < K_) ? (k0 + KCHUNK) : K_;
    const float* fb = feats + (size_t)b * K_ * NN;

    __syncthreads();   // (no LDS deps yet; keeps staging writes ordered below)

    for (int k = k0; k < k1; ++k) {
        const float* fbase = fb + (size_t)k * NN;
        #pragma unroll
        for (int r = 0; r < 2; ++r)
            patchf[slds[r]] = fbase[soff[r]] * swt[r];
        __syncthreads();

        const float cen = patchf[base + R_ * PSTR + R_];
        float ex[HW];
        float dsum = 0.f;
        #pragma unroll
        for (int idx = 0; idx < HW; ++idx) {
            const int we = 2 * idx;                 // even partner tap
            const int u0 = we / D_, v0 = we - u0 * D_;
            const int off0 = u0 * PSTR + v0;        // compile-time immediate
            const int bb = (v0 == 6) ? bX : bN;     // compile-time reg select
            float nb = patchf[bb + off0];
            float t = __expf(fabsf(cen - nb));
            t = ((vmask >> idx) & 1u) ? t : 0.f;
            ex[idx] = t;
            dsum += t;
        }
        // lane pair (same pixel, h=0/1) exchange partial denominators
        const float denom = dsum + __shfl_xor(dsum, 1, 64);
        const float scale = cp[k] * __frcp_rn(denom);   // denom >= 1
        #pragma unroll
        for (int idx = 0; idx < HW; ++idx) Aacc[idx] += scale * ex[idx];
        __syncthreads();
    }

    const int msel = mask[b * NN + gi * N_ + gj];
    if (msel != 0) {
        const int pixg = gi * N_ + gj;
        float* ab = Aout + (size_t)b * W_ * NN + h * NN + pixg;  // plane w=h
        #pragma unroll
        for (int idx = 0; idx < HW; ++idx) {
            if (h == 0 || idx < HW - 1)          // skip w=49 (doesn't exist)
                atomicAdd(ab + idx * (2 * NN), Aacc[idx]);
        }
    }
}

// Kernel B: out[b,q,c] = sum_w A[b,w,p] * x2[b,c,p],  p = q-(u,v), w=(u+3)*7+(v+3)
// Block: 64 consecutive q x 4 c-groups (256 thr). A-taps cached in 49 regs,
// validity folded into the tap. Results staged in LDS -> contiguous store.
__global__ __launch_bounds__(256) void rwn_gather(
    const float* __restrict__ Aarr,  // [B,W,NN]
    const float* __restrict__ x2,    // [B,C,NN]
    float* __restrict__ out)         // [B,NN,C]
{
    __shared__ float obuf[64 * C_];

    const int q0 = blockIdx.x * 64;
    const int b  = blockIdx.y;
    const int tid = threadIdx.x;
    const int qh = tid & 63;         // lane -> consecutive q (coalesced loads)
    const int cg = tid >> 6;         // 0..3 c-group
    const int q = q0 + qh;
    const int i = q >> 7, j = q & (N_ - 1);

    const float* Ab = Aarr + (size_t)b * W_ * NN;
    const float* xb = x2 + (size_t)b * C_ * NN;

    // Load 49 A-taps (c-independent), fold boundary validity, remember p.
    float areg[W_];
    int   poff[W_];
    #pragma unroll
    for (int u = -R_; u <= R_; ++u) {
        const int pi = i - u;
        const int cpi = pi < 0 ? 0 : (pi > N_ - 1 ? N_ - 1 : pi);
        const bool rv = (pi >= 0 && pi < N_);
        #pragma unroll
        for (int v = -R_; v <= R_; ++v) {
            const int w = (u + R_) * D_ + (v + R_);
            const int pj = j - v;
            const int cpj = pj < 0 ? 0 : (pj > N_ - 1 ? N_ - 1 : pj);
            const float vv = (rv && pj >= 0 && pj < N_) ? 1.f : 0.f;
            const int p = cpi * N_ + cpj;
            poff[w] = p;
            areg[w] = vv * Ab[w * NN + p];
        }
    }

    // Each c-group handles c = cg, cg+4, ... (6 or 5 channels)
    for (int c = cg; c < C_; c += 4) {
        const float* xc = xb + (size_t)c * NN;
        float acc = 0.f;
        #pragma unroll
        for (int w = 0; w < W_; ++w)
            acc += areg[w] * xc[poff[w]];
        obuf[qh * C_ + c] = acc;
    }
    __syncthreads();

    // Contiguous cooperative store: 64*21 = 1344 floats
    float* ob = out + (size_t)(b * NN + q0) * C_;
    for (int e = tid; e < 64 * C_; e += 256)
        ob[e] = obuf[e];
}

extern "C" void kernel_launch(void* const* d_in, const int* in_sizes, int n_in,
                              void* d_out, int out_size, void* d_ws, size_t ws_size,
                              hipStream_t stream) {
    const float* feats = (const float*)d_in[0];   // [B,K,N,N]
    const float* x2    = (const float*)d_in[1];   // [B,C,NN]
    const int*   mask  = (const int*)d_in[2];     // [B,N,N]
    const float* cp    = (const float*)d_in[3];   // [K]
    float* out = (float*)d_out;

    float* Aarr = (float*)d_ws;                   // [B,W,NN] fp32
    const size_t Abytes = (size_t)B_ * W_ * NN * sizeof(float);

    hipMemsetAsync(Aarr, 0, Abytes, stream);

    dim3 gridA(128, KC, B_);
    rwn_affinity<<<gridA, 256, 0, stream>>>(feats, mask, cp, Aarr);

    dim3 gridB(NN / 64, B_);
    rwn_gather<<<gridB, 256, 0, stream>>>(Aarr, x2, out);
}

// Round 4
// 178.645 us; speedup vs baseline: 1.0098x; 1.0098x over previous
//
#include <hip/hip_runtime.h>

#define R_ 3
#define D_ 7            // 2R+1
#define W_ 49
#define N_ 128
#define K_ 131
#define C_ 21
#define B_ 2
#define NN (N_ * N_)
#define TI_ 8                   // tile rows
#define TJ_ 16                  // tile cols
#define PROWS (TI_ + 2 * R_)    // 14
#define PCOLS (TJ_ + 2 * R_)    // 22
#define PSTR 24                 // LDS row stride
#define NELEM (PROWS * PCOLS)   // 308 staged elements
#define LDSZ (PROWS * PSTR + 8) // 344 floats (spare slot at 340)
#define KC 8                    // k-chunks per tile
#define KCHUNK ((K_ + KC - 1) / KC)    // 17
#define NTAP 28                 // tap slots per thread: u 0..6, s 0..3, v=2s+h

// Affinity: per-pixel 7x7 window softmax per channel, weighted by cp[k].
// Lane pairs (2t,2t+1) share a pixel; h=tid&1 owns columns v = 2s+h.
// All 28 LDS reads use ONE base (bh) + compile-time offsets -> ds_read2_b32.
// FULLMASK=false (interior tiles): no grid-boundary masking, only phantom v=7.
// Aout layout: [B][W][NN], atomically accumulated across KC k-chunks.
template<bool FULLMASK>
__global__ __launch_bounds__(256) void rwn_affinity_t(
    const float* __restrict__ feats,   // [B,K,N,N]
    const int*   __restrict__ mask,    // [B,N,N]
    const float* __restrict__ cp,      // [K]
    float* __restrict__ Aout)          // [B,W,NN] (pre-zeroed)
{
    __shared__ float patchf[LDSZ];

    // ---- tile decode (interior: 84 tiles, border: 44 tiles) ----
    int tr, tc;
    if (!FULLMASK) {
        const int m = blockIdx.x;          // 0..83
        tr = 1 + m / 6;                    // 1..14
        tc = 1 + m % 6;                    // 1..6
    } else {
        const int m = blockIdx.x;          // 0..43
        if (m < 8)       { tr = 0;          tc = m; }
        else if (m < 16) { tr = 15;         tc = m - 8; }
        else if (m < 30) { tr = 1 + m - 16; tc = 0; }
        else             { tr = 1 + m - 30; tc = 7; }
    }
    const int kc = blockIdx.y;
    const int b  = blockIdx.z;
    const int ti0 = tr * TI_, tj0 = tc * TJ_;

    const int tid = threadIdx.x;
    const int pix = tid >> 1;              // 0..127
    const int h   = tid & 1;               // column-parity owner
    const int ti = pix >> 4;               // 0..7
    const int tj = pix & 15;               // 0..15
    const int gi = ti0 + ti, gj = tj0 + tj;

    // ---- hoisted staging setup: thread owns elements tid and 256+tid ----
    int   soff[2];
    float swt[2];
    int   slds[2];
    #pragma unroll
    for (int r = 0; r < 2; ++r) {
        int e = tid + r * 256;
        bool act = (e < NELEM);
        int pr = e / PCOLS, pc = e - pr * PCOLS;
        int mi = ti0 + pr - R_, mj = tj0 + pc - R_;
        bool valid = act && mi >= 0 && mi < N_ && mj >= 0 && mj < N_;
        int cmi = mi < 0 ? 0 : (mi > N_ - 1 ? N_ - 1 : mi);
        int cmj = mj < 0 ? 0 : (mj > N_ - 1 ? N_ - 1 : mj);
        soff[r] = cmi * N_ + cmj;
        swt[r]  = valid ? (float)mask[b * NN + soff[r]] : 0.f;
        slds[r] = act ? (pr * PSTR + pc) : (PROWS * PSTR + 4);  // spare slot
    }

    // Masking data
    unsigned int vmask = 0u;               // border path: per-tap validity
    if (FULLMASK) {
        #pragma unroll
        for (int u = 0; u < D_; ++u)
            #pragma unroll
            for (int s = 0; s < 4; ++s) {
                int v = 2 * s + h;
                int ni = gi + u - R_, nj = gj + v - R_;
                if (v <= 6 && ni >= 0 && ni < N_ && nj >= 0 && nj < N_)
                    vmask |= (1u << (u * 4 + s));
            }
    }
    const float ph = h ? 0.f : 1.f;        // interior path: phantom v=7 killer

    const int cbase = ti * PSTR + tj;      // patch addr of (pixel - (3,3))
    const int bh = cbase + h;              // single base for all 28 taps

    float Aacc[NTAP];
    #pragma unroll
    for (int i = 0; i < NTAP; ++i) Aacc[i] = 0.f;

    const int k0 = kc * KCHUNK;
    const int k1 = (k0 + KCHUNK < K_) ? (k0 + KCHUNK) : K_;
    const float* fb = feats + (size_t)b * K_ * NN;

    // software prefetch of first k
    const float* fk0 = fb + (size_t)k0 * NN;
    float pre0 = fk0[soff[0]] * swt[0];
    float pre1 = fk0[soff[1]] * swt[1];

    __syncthreads();

    for (int k = k0; k < k1; ++k) {
        patchf[slds[0]] = pre0;
        patchf[slds[1]] = pre1;
        // prefetch next k while this one computes
        float n0 = 0.f, n1 = 0.f;
        if (k + 1 < k1) {
            const float* fn = fb + (size_t)(k + 1) * NN;
            n0 = fn[soff[0]] * swt[0];
            n1 = fn[soff[1]] * swt[1];
        }
        __syncthreads();

        const float cen = patchf[cbase + R_ * PSTR + R_];
        float ex[NTAP];
        float dsum = 0.f;
        #pragma unroll
        for (int u = 0; u < D_; ++u) {
            #pragma unroll
            for (int s = 0; s < 4; ++s) {
                const int idx = u * 4 + s;
                float nb = patchf[bh + u * PSTR + 2 * s];   // imm offset, one base
                float t = __expf(fabsf(cen - nb));
                if (FULLMASK) {
                    t = ((vmask >> idx) & 1u) ? t : 0.f;
                } else if (s == 3) {
                    t *= ph;                                 // kill phantom v=7
                }
                ex[idx] = t;
                dsum += t;
            }
        }
        const float denom = dsum + __shfl_xor(dsum, 1, 64); // lane pair = pixel
        const float scale = cp[k] * __frcp_rn(denom);       // denom >= 1
        #pragma unroll
        for (int idx = 0; idx < NTAP; ++idx) Aacc[idx] += scale * ex[idx];
        __syncthreads();

        pre0 = n0; pre1 = n1;
    }

    if (mask[b * NN + gi * N_ + gj] != 0) {
        const int pixg = gi * N_ + gj;
        float* ab = Aout + (size_t)b * W_ * NN + h * NN + pixg;
        #pragma unroll
        for (int u = 0; u < D_; ++u) {
            #pragma unroll
            for (int s = 0; s < 4; ++s) {
                if (h == 0 || s < 3)   // h=1,s=3 is the phantom v=7 slot
                    atomicAdd(ab + (u * D_ + 2 * s) * NN, Aacc[u * 4 + s]);
            }
        }
    }
}

// Kernel B (R2 form): out[b,q,c] = sum_w A[b,w,p]*x2[b,c,p], p=q-(u,v).
// Branchless: clamp address, multiply by 0/1 validity.
__global__ __launch_bounds__(256) void rwn_gather(
    const float* __restrict__ Aarr,  // [B,W,NN]
    const float* __restrict__ x2,    // [B,C,NN]
    float* __restrict__ out)         // [B,NN,C]
{
    const int t = blockIdx.x * 256 + threadIdx.x;
    if (t >= B_ * C_ * NN) return;
    const int q  = t & (NN - 1);
    const int bc = t >> 14;
    const int b  = bc / C_;
    const int c  = bc - b * C_;
    const int i = q >> 7, j = q & (N_ - 1);

    const float* Ab = Aarr + (size_t)b * W_ * NN;
    const float* xb = x2 + (size_t)(b * C_ + c) * NN;

    float acc = 0.f;
    #pragma unroll
    for (int u = -R_; u <= R_; ++u) {
        const int pi = i - u;
        const int cpi = pi < 0 ? 0 : (pi > N_ - 1 ? N_ - 1 : pi);
        const float rowv = (pi >= 0 && pi < N_) ? 1.f : 0.f;
        #pragma unroll
        for (int v = -R_; v <= R_; ++v) {
            const int w = (u + R_) * D_ + (v + R_);
            const int pj = j - v;
            const int cpj = pj < 0 ? 0 : (pj > N_ - 1 ? N_ - 1 : pj);
            const float vv = (pj >= 0 && pj < N_) ? rowv : 0.f;
            const int p = cpi * N_ + cpj;
            acc += vv * Ab[w * NN + p] * xb[p];
        }
    }
    out[(size_t)(b * NN + q) * C_ + c] = acc;
}

extern "C" void kernel_launch(void* const* d_in, const int* in_sizes, int n_in,
                              void* d_out, int out_size, void* d_ws, size_t ws_size,
                              hipStream_t stream) {
    const float* feats = (const float*)d_in[0];   // [B,K,N,N]
    const float* x2    = (const float*)d_in[1];   // [B,C,NN]
    const int*   mask  = (const int*)d_in[2];     // [B,N,N]
    const float* cp    = (const float*)d_in[3];   // [K]
    float* out = (float*)d_out;

    float* Aarr = (float*)d_ws;                   // [B,W,NN] fp32
    const size_t Abytes = (size_t)B_ * W_ * NN * sizeof(float);

    hipMemsetAsync(Aarr, 0, Abytes, stream);

    dim3 gridI(84, KC, B_);   // interior tiles: no boundary masking
    rwn_affinity_t<false><<<gridI, 256, 0, stream>>>(feats, mask, cp, Aarr);
    dim3 gridB(44, KC, B_);   // border tiles: full masking
    rwn_affinity_t<true><<<gridB, 256, 0, stream>>>(feats, mask, cp, Aarr);

    const int total = B_ * C_ * NN;
    rwn_gather<<<(total + 255) / 256, 256, 0, stream>>>(Aarr, x2, out);
}

// Round 5
// 154.211 us; speedup vs baseline: 1.1698x; 1.1584x over previous
//
#include <hip/hip_runtime.h>

#define R_ 3
#define D_ 7            // 2R+1
#define W_ 49
#define N_ 128
#define K_ 131
#define C_ 21
#define B_ 2
#define NN (N_ * N_)
#define TI_ 8                   // tile rows
#define TJ_ 16                  // tile cols
#define PROWS (TI_ + 2 * R_)    // 14
#define PCOLS (TJ_ + 2 * R_)    // 22
#define PSTR 24                 // LDS row stride (in float2 pairs)
#define NELEM (PROWS * PCOLS)   // 308 staged elements
#define LDSP (PROWS * PSTR + 8) // 344 pairs (spare write slot at 340)
#define KC 8                    // k-chunks per tile
#define KCHUNK ((K_ + KC - 1) / KC)    // 17
#define NTAP 28                 // tap slots per thread: u 0..6, s 0..3, v=2s+h

// Affinity: per-pixel 7x7 window softmax per channel, weighted by cp[k].
// Trick: exp(|c-n|) = max(Ec*EnInv, En*EcInv) with (E,Einv)=exp(+/-val) pairs
// computed once per staged element. OOB elements store (0,0) -> taps auto-zero,
// so ONE kernel covers interior and border tiles with no per-tap masking.
// Lane pairs (2t,2t+1) share a pixel; h=tid&1 owns columns v=2s+h.
// Aout layout: [B][W][NN], atomically accumulated across KC k-chunks.
__global__ __launch_bounds__(256) void rwn_affinity(
    const float* __restrict__ feats,   // [B,K,N,N]
    const int*   __restrict__ mask,    // [B,N,N]
    const float* __restrict__ cp,      // [K]
    float* __restrict__ Aout)          // [B,W,NN] (pre-zeroed)
{
    __shared__ float2 patch2[LDSP];

    const int tile = blockIdx.x;           // 0..127 (16x8 tiles of 8x16)
    const int kc   = blockIdx.y;
    const int b    = blockIdx.z;
    const int tr = tile >> 3, tc = tile & 7;
    const int ti0 = tr * TI_, tj0 = tc * TJ_;

    const int tid = threadIdx.x;
    const int pix = tid >> 1;              // 0..127
    const int h   = tid & 1;               // column-parity owner
    const int ti = pix >> 4;               // 0..7
    const int tj = pix & 15;               // 0..15
    const int gi = ti0 + ti, gj = tj0 + tj;

    // ---- hoisted staging setup: thread owns elements tid and 256+tid ----
    int   soff[2];      // clamped global offset
    float swt[2];       // in-bounds * mask   (0 -> staged val 0)
    float ozw[2];       // 0 for OOB (store zero pair), 1 otherwise
    int   slds[2];      // pair index in LDS
    #pragma unroll
    for (int r = 0; r < 2; ++r) {
        int e = tid + r * 256;
        bool act = (e < NELEM);
        int pr = e / PCOLS, pc = e - pr * PCOLS;
        int mi = ti0 + pr - R_, mj = tj0 + pc - R_;
        bool inb = act && mi >= 0 && mi < N_ && mj >= 0 && mj < N_;
        int cmi = mi < 0 ? 0 : (mi > N_ - 1 ? N_ - 1 : mi);
        int cmj = mj < 0 ? 0 : (mj > N_ - 1 ? N_ - 1 : mj);
        soff[r] = cmi * N_ + cmj;
        swt[r]  = inb ? (float)mask[b * NN + soff[r]] : 0.f;
        ozw[r]  = inb ? 1.f : 0.f;
        slds[r] = act ? (pr * PSTR + pc) : (PROWS * PSTR + 4);  // spare slot
    }

    const float ph = h ? 0.f : 1.f;        // kills phantom v=7 taps (h=1,s=3)
    const int cbase = ti * PSTR + tj;      // pair addr of (pixel - (3,3))
    const int bh = cbase + h;              // single base for all 28 taps

    float Aacc[NTAP];
    #pragma unroll
    for (int i = 0; i < NTAP; ++i) Aacc[i] = 0.f;

    const int k0 = kc * KCHUNK;
    const int k1 = (k0 + KCHUNK < K_) ? (k0 + KCHUNK) : K_;
    const float* fb = feats + (size_t)b * K_ * NN;

    // zero-init all LDS pairs once: pad columns / spare slot stay 0 forever
    for (int e = tid; e < LDSP; e += 256) patch2[e] = make_float2(0.f, 0.f);

    // software prefetch of first k (already mask-weighted)
    const float* fk0 = fb + (size_t)k0 * NN;
    float pre0 = fk0[soff[0]] * swt[0];
    float pre1 = fk0[soff[1]] * swt[1];

    __syncthreads();

    for (int k = k0; k < k1; ++k) {
        patch2[slds[0]] = make_float2(ozw[0] * __expf(pre0), ozw[0] * __expf(-pre0));
        patch2[slds[1]] = make_float2(ozw[1] * __expf(pre1), ozw[1] * __expf(-pre1));
        // prefetch next k while this one computes
        float n0 = 0.f, n1 = 0.f;
        if (k + 1 < k1) {
            const float* fn = fb + (size_t)(k + 1) * NN;
            n0 = fn[soff[0]] * swt[0];
            n1 = fn[soff[1]] * swt[1];
        }
        __syncthreads();

        const float2 cpair = patch2[cbase + R_ * PSTR + R_];
        float ex[NTAP];
        float dsum = 0.f;
        #pragma unroll
        for (int u = 0; u < D_; ++u) {
            #pragma unroll
            for (int s = 0; s < 4; ++s) {
                const int idx = u * 4 + s;
                const float2 np = patch2[bh + u * PSTR + 2 * s]; // imm offset
                float t = fmaxf(cpair.x * np.y, np.x * cpair.y); // exp(|c-n|)
                if (s == 3) t *= ph;                             // phantom v=7
                ex[idx] = t;
                dsum += t;
            }
        }
        const float denom = dsum + __shfl_xor(dsum, 1, 64);  // lane pair = pixel
        const float scale = cp[k] * __frcp_rn(denom);        // denom >= ~1
        #pragma unroll
        for (int idx = 0; idx < NTAP; ++idx) Aacc[idx] += scale * ex[idx];
        __syncthreads();

        pre0 = n0; pre1 = n1;
    }

    if (mask[b * NN + gi * N_ + gj] != 0) {
        const int pixg = gi * N_ + gj;
        float* ab = Aout + (size_t)b * W_ * NN + h * NN + pixg;
        #pragma unroll
        for (int u = 0; u < D_; ++u) {
            #pragma unroll
            for (int s = 0; s < 4; ++s) {
                if (h == 0 || s < 3)   // h=1,s=3 is the phantom v=7 slot
                    atomicAdd(ab + (u * D_ + 2 * s) * NN, Aacc[u * 4 + s]);
            }
        }
    }
}

// Gather: out[b,q,c] = sum_w A[b,w,p]*x2[b,c,p], p=q-(u-3,v-3).
// Block = 64 q x 4 w-groups. wg owns u in {wg, wg+4}; 21 c-accumulators in
// registers (each A/x2 load amortized over 21 FMAs). LDS reduce over wgs,
// then one contiguous coalesced store. No atomics.
#define RSTR 25   // LDS reduce stride (odd -> conflict-free)
__global__ __launch_bounds__(256) void rwn_gather(
    const float* __restrict__ Aarr,  // [B,W,NN]
    const float* __restrict__ x2,    // [B,C,NN]
    float* __restrict__ out)         // [B,NN,C]
{
    __shared__ float red[4 * 64 * RSTR];   // 25.6 KB

    const int q0 = blockIdx.x * 64;
    const int b  = blockIdx.y;
    const int tid = threadIdx.x;
    const int qh = tid & 63;         // lane -> consecutive q (coalesced)
    const int wg = tid >> 6;         // wave-uniform w-group
    const int q = q0 + qh;
    const int i = q >> 7, j = q & (N_ - 1);

    const float* Ab = Aarr + (size_t)b * W_ * NN;
    const float* xb = x2 + (size_t)b * C_ * NN;

    float acc[C_];
    #pragma unroll
    for (int c = 0; c < C_; ++c) acc[c] = 0.f;

    #pragma unroll
    for (int rep = 0; rep < 2; ++rep) {
        const int uu = wg + rep * 4;             // 0..7 (wave-uniform)
        if (uu > 6) break;                       // wg==3 second rep
        const int pi = i - (uu - R_);
        const int cpi = pi < 0 ? 0 : (pi > N_ - 1 ? N_ - 1 : pi);
        const float rv = (pi >= 0 && pi < N_) ? 1.f : 0.f;
        const float* Aw = Ab + (size_t)uu * D_ * NN;
        #pragma unroll
        for (int v = 0; v < D_; ++v) {
            const int pj = j - (v - R_);
            const int cpj = pj < 0 ? 0 : (pj > N_ - 1 ? N_ - 1 : pj);
            const float vv = (pj >= 0 && pj < N_) ? rv : 0.f;
            const int p = cpi * N_ + cpj;
            const float a = vv * Aw[(size_t)v * NN + p];
            #pragma unroll
            for (int c = 0; c < C_; ++c)
                acc[c] += a * xb[(size_t)c * NN + p];
        }
    }

    // stage per-wg partials
    float* rbase = red + (wg * 64 + qh) * RSTR;
    #pragma unroll
    for (int c = 0; c < C_; ++c) rbase[c] = acc[c];
    __syncthreads();

    // reduce 4 wg-planes and store contiguous (64*21 = 1344 floats)
    float* ob = out + ((size_t)b * NN + q0) * C_;
    for (int e = tid; e < 64 * C_; e += 256) {
        const int qq = e / C_, cc = e - qq * C_;   // const-div (magic mul)
        const int a = qq * RSTR + cc;
        ob[e] = red[a] + red[64 * RSTR + a] + red[128 * RSTR + a] + red[192 * RSTR + a];
    }
}

extern "C" void kernel_launch(void* const* d_in, const int* in_sizes, int n_in,
                              void* d_out, int out_size, void* d_ws, size_t ws_size,
                              hipStream_t stream) {
    const float* feats = (const float*)d_in[0];   // [B,K,N,N]
    const float* x2    = (const float*)d_in[1];   // [B,C,NN]
    const int*   mask  = (const int*)d_in[2];     // [B,N,N]
    const float* cp    = (const float*)d_in[3];   // [K]
    float* out = (float*)d_out;

    float* Aarr = (float*)d_ws;                   // [B,W,NN] fp32
    const size_t Abytes = (size_t)B_ * W_ * NN * sizeof(float);

    hipMemsetAsync(Aarr, 0, Abytes, stream);

    dim3 gridA(128, KC, B_);
    rwn_affinity<<<gridA, 256, 0, stream>>>(feats, mask, cp, Aarr);

    dim3 gridG(NN / 64, B_);
    rwn_gather<<<gridG, 256, 0, stream>>>(Aarr, x2, out);
}